// Round 3
// baseline (1953.433 us; speedup 1.0000x reference)
//
#include <hip/hip_runtime.h>
#include <hip/hip_bf16.h>

// ---------------- problem constants ----------------
#define BB   128
#define SS   2048
#define NPOS 262144L   // BB*SS
#define MM   50
#define DK   64
#define DV   128
#define DS   50
#define KN   5

// ---------------- workspace layout (byte offsets) ----------------
// [0, 256KB)   : weight block (fp32 consts + bf16 transposed erase/add)
// [256KB, ..)  : attn bf16 [NPOS][64] (cols 50..63 zero-padded)   33.5 MB
// next         : ea   bf16 [NPOS][256] (erase | add)             134.2 MB
// next         : v    bf16 [NPOS][128]  -- ALIASED later by reads 67.1 MB
#define EWT_OFF   131072L     // u16 erase_w^T [128][128]
#define AWT_OFF   163840L     // u16 add_w^T   [128][128]
#define ATTN_OFF  262144L
#define EA_OFF    33816576L
#define V_OFF     168034304L
#define WS_NEEDED 235143168L

// fp32 weight block offsets (floats)
#define KMo  0       // key_mem [50][64]
#define VPWo 3200    // value_proj_w TRANSPOSED [128][69]
#define VPBo 12032   // value_proj_b [128]
#define SWo  12160   // summary_w TRANSPOSED [50][192]
#define SBo  21760   // summary_b [50]
#define TWo  21810   // theta_w [50]
#define AWo  21860   // alpha_w [64]
#define BWo  21924   // beta_w TRANSPOSED [4][64]
#define SCo  22180   // [0]=theta_b [1]=alpha_b [2..5]=beta_b

typedef unsigned short u16;
typedef __attribute__((ext_vector_type(8))) short   short8;
typedef __attribute__((ext_vector_type(8))) __bf16  bf16x8;
typedef __attribute__((ext_vector_type(4))) float   floatx4;

static __device__ __forceinline__ float b2f(u16 u) {
    union { unsigned int i; float f; } x; x.i = ((unsigned int)u) << 16; return x.f;
}
static __device__ __forceinline__ u16 f2b(float f) {
    union { float f; unsigned int i; } x; x.f = f;
    unsigned int i = x.i;
    return (u16)((i + 0x7fffu + ((i >> 16) & 1u)) >> 16);
}
static __device__ __forceinline__ float fast_tanh(float x) {
    float xc = fminf(15.f, fmaxf(-15.f, x));
    float t = __expf(2.f * xc);
    return (t - 1.f) / (t + 1.f);
}

// ---------------- kprep: pack fp32 weights (+transposes, bf16 for MFMA) ----------------
__global__ __launch_bounds__(256) void kprep(
    const float* km, const float* vpw, const float* vpb,
    const float* sw, const float* sb, const float* tw, const float* tb,
    const float* aw, const float* ab, const float* bw, const float* bb,
    const float* ew_, const float* adw_,
    float* wf, u16* ewt, u16* awt)
{
    int tid = threadIdx.x;
    for (int i = tid; i < 3200; i += 256) wf[KMo + i] = km[i];
    for (int i = tid; i < 8832; i += 256) {           // vpw_t[j][k] = vpw[k][j]
        int j = i / 69, k = i - j * 69;
        wf[VPWo + i] = vpw[k * 128 + j];
    }
    for (int i = tid; i < 128; i += 256) wf[VPBo + i] = vpb[i];
    for (int i = tid; i < 9600; i += 256) {           // sw_t[j][k] = sw[k][j]
        int j = i / 192, k = i - j * 192;
        wf[SWo + i] = sw[k * 50 + j];
    }
    for (int i = tid; i < 50; i += 256) wf[SBo + i] = sb[i];
    for (int i = tid; i < 50; i += 256) wf[TWo + i] = tw[i];
    for (int i = tid; i < 64; i += 256) wf[AWo + i] = aw[i];
    for (int i = tid; i < 256; i += 256) {            // bw_t[j][k] = bw[k][j]
        int j = i >> 6, k = i & 63;
        wf[BWo + i] = bw[k * 4 + j];
    }
    for (int i = tid; i < 16384; i += 256) {          // transpose erase/add -> bf16
        int n = i >> 7, k = i & 127;
        ewt[i] = f2b(ew_[k * 128 + n]);
        awt[i] = f2b(adw_[k * 128 + n]);
    }
    if (tid == 0) wf[SCo + 0] = tb[0];
    if (tid == 1) wf[SCo + 1] = ab[0];
    if (tid >= 2 && tid < 6) wf[SCo + tid] = bb[tid - 2];
}

// ---------------- ka: attn softmax + value projection (lane = position) ----------------
__global__ __launch_bounds__(64) void ka(
    const int* __restrict__ questions, const int* __restrict__ responses,
    const float* __restrict__ qe_w, const float* __restrict__ iv_w,
    const float* __restrict__ wf,
    u16* __restrict__ ws_attn, u16* __restrict__ ws_v)
{
    __shared__ float lgs[64 * 51];
    int lane = threadIdx.x;
    long pos = (long)blockIdx.x * 64 + lane;
    int q = questions[pos];

    // ---- load q_e row (fp32) into registers ----
    float qe[64];
    const float* qrow = qe_w + (long)q * 64;
    #pragma unroll
    for (int c = 0; c < 16; ++c) {
        floatx4 vv = *(const floatx4*)(qrow + c * 4);
        qe[c*4+0] = vv[0]; qe[c*4+1] = vv[1]; qe[c*4+2] = vv[2]; qe[c*4+3] = vv[3];
    }
    // ---- attn logits (key_mem wave-uniform -> scalar loads) ----
    const float* kmf = wf + KMo;
    for (int m = 0; m < 50; ++m) {
        float acc = 0.f;
        #pragma unroll
        for (int k = 0; k < 64; ++k) acc = fmaf(qe[k], kmf[m * 64 + k], acc);
        lgs[lane * 51 + m] = acc;
    }
    // ---- in-lane softmax over 50 ----
    float mx = -1e30f;
    for (int m = 0; m < 50; ++m) mx = fmaxf(mx, lgs[lane * 51 + m]);
    float sum = 0.f;
    for (int m = 0; m < 50; ++m) {
        float e = __expf(lgs[lane * 51 + m] - mx);
        sum += e; lgs[lane * 51 + m] = e;
    }
    float inv = 1.f / sum;
    // ---- write attn bf16 [pos][64], cols 50..63 zeroed ----
    u16* adst = ws_attn + pos * 64;
    #pragma unroll
    for (int c = 0; c < 8; ++c) {
        short8 w;
        #pragma unroll
        for (int j = 0; j < 8; ++j) {
            int m = c * 8 + j;
            float val = (m < 50) ? lgs[lane * 51 + m] * inv : 0.f;
            w[j] = (short)f2b(val);
        }
        *(short8*)(adst + c * 8) = w;
    }

    // ---- value embedding: cat = [item_v(64), resp_feat(5)] ----
    float cat[69];
    const float* irow = iv_w + (long)q * 64;
    #pragma unroll
    for (int c = 0; c < 16; ++c) {
        floatx4 vv = *(const floatx4*)(irow + c * 4);
        cat[c*4+0] = vv[0]; cat[c*4+1] = vv[1]; cat[c*4+2] = vv[2]; cat[c*4+3] = vv[3];
    }
    int r = responses[pos];
    #pragma unroll
    for (int kk = 0; kk < KN; ++kk)
        cat[64 + kk] = fmaxf(1.f - fabsf((float)kk - (float)r) * 0.25f, 0.f);

    const float* vt = wf + VPWo;
    const float* vb = wf + VPBo;
    u16* vdst = ws_v + pos * 128;
    for (int jc = 0; jc < 16; ++jc) {
        short8 wv;
        #pragma unroll
        for (int jj = 0; jj < 8; ++jj) {
            int j = jc * 8 + jj;
            float acc = vb[j];
            #pragma unroll
            for (int k = 0; k < 69; ++k) acc = fmaf(cat[k], vt[j * 69 + k], acc);
            wv[jj] = (short)f2b(acc);
        }
        *(short8*)(vdst + jc * 8) = wv;
    }
}

// ---------------- kb: erase/add GEMM via MFMA + fused activation ----------------
// grid = (NPOS/128)*2 ; blockIdx: rowblock = bid>>1, nh = bid&1 (0=erase,1=add)
__global__ __launch_bounds__(256) void kb(
    const u16* __restrict__ ws_v,
    const u16* __restrict__ ewt, const float* __restrict__ erase_b,
    const u16* __restrict__ awt, const float* __restrict__ add_b,
    u16* __restrict__ ws_ea)
{
    __shared__ u16 Asm[128 * 128];   // 32 KB, XOR-swizzled [pos][k]
    __shared__ u16 Bsm[128 * 128];   // 32 KB, XOR-swizzled [n][k]
    int tid = threadIdx.x;
    int nh = blockIdx.x & 1;
    long rowbase = (long)(blockIdx.x >> 1) * 128;
    const u16*   WT   = nh ? awt : ewt;        // [n][k] bf16
    const float* bvec = nh ? add_b : erase_b;  // fp32

    for (int c = tid; c < 2048; c += 256) {
        int p = c >> 4, k0 = (c & 15) * 8;
        short8 vv = *(const short8*)(ws_v + (rowbase + p) * 128 + k0);
        int cx = (k0 >> 3) ^ (p & 15);
        *(short8*)&Asm[p * 128 + cx * 8] = vv;
    }
    for (int c = tid; c < 2048; c += 256) {
        int n = c >> 4, k0 = (c & 15) * 8;
        short8 vv = *(const short8*)(WT + n * 128 + k0);
        int cx = (k0 >> 3) ^ (n & 15);
        *(short8*)&Bsm[n * 128 + cx * 8] = vv;
    }
    __syncthreads();

    int w = tid >> 6, lane = tid & 63;
    int lrow = lane & 15, quad = lane >> 4;
    floatx4 acc[8][2];
    #pragma unroll
    for (int mi = 0; mi < 8; ++mi)
        #pragma unroll
        for (int nj = 0; nj < 2; ++nj) acc[mi][nj] = (floatx4)0.f;

    #pragma unroll
    for (int kb4 = 0; kb4 < 4; ++kb4) {
        int cx = (kb4 * 4 + quad) ^ lrow;
        bf16x8 afr[8], bfr[2];
        #pragma unroll
        for (int mi = 0; mi < 8; ++mi)
            afr[mi] = *(const bf16x8*)&Asm[(mi * 16 + lrow) * 128 + cx * 8];
        #pragma unroll
        for (int nj = 0; nj < 2; ++nj)
            bfr[nj] = *(const bf16x8*)&Bsm[(w * 32 + nj * 16 + lrow) * 128 + cx * 8];
        #pragma unroll
        for (int mi = 0; mi < 8; ++mi)
            #pragma unroll
            for (int nj = 0; nj < 2; ++nj)
                acc[mi][nj] = __builtin_amdgcn_mfma_f32_16x16x32_bf16(
                    afr[mi], bfr[nj], acc[mi][nj], 0, 0, 0);
    }
    #pragma unroll
    for (int mi = 0; mi < 8; ++mi) {
        #pragma unroll
        for (int nj = 0; nj < 2; ++nj) {
            int ncol = w * 32 + nj * 16 + lrow;
            float bs = bvec[ncol];
            #pragma unroll
            for (int r = 0; r < 4; ++r) {
                int row = mi * 16 + quad * 4 + r;
                float x = acc[mi][nj][r] + bs;
                float y = nh ? fast_tanh(x) : 1.f / (1.f + __expf(-x));
                ws_ea[(rowbase + row) * 256L + nh * 128 + ncol] = f2b(y);
            }
        }
    }
}

// ---------------- k2: the sequential memory scan ----------------
// grid = 256 (b x v-half), block = 512: vl = tid&63, h = tid>>6 owns 7 m-rows
__global__ __launch_bounds__(512) void k2(
    const u16* __restrict__ ws_attn, const u16* __restrict__ ws_ea,
    const float* __restrict__ init_mem, u16* __restrict__ ws_reads)
{
    __shared__ float attn_s[64];
    __shared__ float part[8][64];
    int b = blockIdx.x >> 1, vh = blockIdx.x & 1;
    int tid = threadIdx.x;
    int vl = tid & 63, h = tid >> 6;
    int v = vh * 64 + vl;
    const int m0 = h * 7;

    float mem[7];
    #pragma unroll
    for (int i = 0; i < 7; ++i) {
        int m = m0 + i;
        mem[i] = (m < 50) ? init_mem[m * 128 + v] : 0.f;
    }
    long base = (long)b * SS;
    float at_r = 0.f;
    if (tid < 64) at_r = b2f(ws_attn[base * 64 + tid]);
    float e_r = b2f(ws_ea[base * 256 + v]);
    float a_r = b2f(ws_ea[base * 256 + 128 + v]);

    for (int t = 0; t < SS; ++t) {
        if (tid < 64) attn_s[tid] = at_r;
        float e = e_r, a = a_r;
        if (t + 1 < SS) {
            long p1 = base + t + 1;
            if (tid < 64) at_r = b2f(ws_attn[p1 * 64 + tid]);
            e_r = b2f(ws_ea[p1 * 256 + v]);
            a_r = b2f(ws_ea[p1 * 256 + 128 + v]);
        }
        __syncthreads();
        float partial = 0.f;
        #pragma unroll
        for (int i = 0; i < 7; ++i) {
            float wgt = attn_s[m0 + i];
            partial = fmaf(wgt, mem[i], partial);             // read (old mem)
            mem[i] = fmaf(wgt, fmaf(-e, mem[i], a), mem[i]);  // update
        }
        part[h][vl] = partial;
        __syncthreads();
        if (h == 0) {
            float r = 0.f;
            #pragma unroll
            for (int hh = 0; hh < 8; ++hh) r += part[hh][vl];
            ws_reads[(base + t) * 128 + v] = f2b(r);
        }
    }
}

// ---------------- k3: summary/theta/alpha/beta/logits/probs (lane = position) ----------------
__global__ __launch_bounds__(64) void k3(
    const int* __restrict__ questions, const float* __restrict__ qe_w,
    const u16* __restrict__ ws_reads, const float* __restrict__ wf,
    float* __restrict__ out)
{
    __shared__ float accs[64 * 51];
    int lane = threadIdx.x;
    long pos = (long)blockIdx.x * 64 + lane;
    int q = questions[pos];
    const float* swt = wf + SWo;
    const u16* rrow = ws_reads + pos * 128;

    // chunk 0: cat[0..95] = reads[0..95]
    float c[96];
    #pragma unroll
    for (int ch = 0; ch < 12; ++ch) {
        short8 vv = *(const short8*)(rrow + ch * 8);
        #pragma unroll
        for (int i = 0; i < 8; ++i) c[ch * 8 + i] = b2f((u16)vv[i]);
    }
    for (int j = 0; j < 50; ++j) {
        float acc = wf[SBo + j];
        #pragma unroll
        for (int k = 0; k < 96; ++k) acc = fmaf(c[k], swt[j * 192 + k], acc);
        accs[lane * 51 + j] = acc;
    }
    // chunk 1: cat[96..191] = reads[96..127] + q_e[0..63]
    #pragma unroll
    for (int ch = 0; ch < 4; ++ch) {
        short8 vv = *(const short8*)(rrow + 96 + ch * 8);
        #pragma unroll
        for (int i = 0; i < 8; ++i) c[ch * 8 + i] = b2f((u16)vv[i]);
    }
    const float* qrow = qe_w + (long)q * 64;
    #pragma unroll
    for (int ch = 0; ch < 16; ++ch) {
        floatx4 vv = *(const floatx4*)(qrow + ch * 4);
        c[32 + ch*4+0] = vv[0]; c[32 + ch*4+1] = vv[1];
        c[32 + ch*4+2] = vv[2]; c[32 + ch*4+3] = vv[3];
    }
    float dot = 0.f;
    for (int j = 0; j < 50; ++j) {
        float acc = accs[lane * 51 + j];
        #pragma unroll
        for (int k = 0; k < 96; ++k) acc = fmaf(c[k], swt[j * 192 + 96 + k], acc);
        dot = fmaf(fast_tanh(acc), wf[TWo + j], dot);
    }
    float theta = fast_tanh(dot + wf[SCo + 0]);

    float bet[4];
    #pragma unroll
    for (int j = 0; j < 4; ++j) {
        float acc = wf[SCo + 2 + j];
        #pragma unroll
        for (int k = 0; k < 64; ++k) acc = fmaf(c[32 + k], wf[BWo + j * 64 + k], acc);
        bet[j] = acc;
    }
    float al = wf[SCo + 1];
    #pragma unroll
    for (int k = 0; k < 64; ++k) al = fmaf(c[32 + k], wf[AWo + k], al);
    float alpha = (al > 20.f) ? al : log1pf(__expf(al));

    float inter = theta * alpha;
    float l1 = inter - bet[0];
    float l2 = l1 + inter - bet[1];
    float l3 = l2 + inter - bet[2];
    float l4 = l3 + inter - bet[3];
    float mx = fmaxf(0.f, fmaxf(fmaxf(l1, l2), fmaxf(l3, l4)));
    float e0 = __expf(0.f - mx), e1 = __expf(l1 - mx), e2 = __expf(l2 - mx);
    float e3 = __expf(l3 - mx), e4 = __expf(l4 - mx);
    float inv = 1.f / (e0 + e1 + e2 + e3 + e4);

    out[pos] = theta;
    out[NPOS + pos] = alpha;
    float* ob = out + 2L * NPOS + pos * 4;
    ob[0] = bet[0]; ob[1] = bet[1]; ob[2] = bet[2]; ob[3] = bet[3];
    float* ol = out + 6L * NPOS + pos * 5;
    ol[0] = 0.f; ol[1] = l1; ol[2] = l2; ol[3] = l3; ol[4] = l4;
    float* op = out + 11L * NPOS + pos * 5;
    op[0] = e0 * inv; op[1] = e1 * inv; op[2] = e2 * inv;
    op[3] = e3 * inv; op[4] = e4 * inv;
}

// ---------------- host launcher ----------------
extern "C" void kernel_launch(void* const* d_in, const int* in_sizes, int n_in,
                              void* d_out, int out_size, void* d_ws, size_t ws_size,
                              hipStream_t stream)
{
    if (ws_size < (size_t)WS_NEEDED) return;   // clean fail beats OOB fault

    const int*   questions = (const int*)d_in[0];
    const int*   responses = (const int*)d_in[1];
    const float* qe_w      = (const float*)d_in[2];
    const float* iv_w      = (const float*)d_in[3];
    const float* vp_w      = (const float*)d_in[4];
    const float* vp_b      = (const float*)d_in[5];
    const float* key_mem   = (const float*)d_in[6];
    const float* init_mem  = (const float*)d_in[7];
    const float* erase_w   = (const float*)d_in[8];
    const float* erase_b   = (const float*)d_in[9];
    const float* add_w     = (const float*)d_in[10];
    const float* add_b     = (const float*)d_in[11];
    const float* summary_w = (const float*)d_in[12];
    const float* summary_b = (const float*)d_in[13];
    const float* theta_w   = (const float*)d_in[14];
    const float* theta_b   = (const float*)d_in[15];
    const float* alpha_w   = (const float*)d_in[16];
    const float* alpha_b   = (const float*)d_in[17];
    const float* beta_w    = (const float*)d_in[18];
    const float* beta_b    = (const float*)d_in[19];

    char* ws = (char*)d_ws;
    float* wf       = (float*)ws;
    u16*   ewt      = (u16*)(ws + EWT_OFF);
    u16*   awt      = (u16*)(ws + AWT_OFF);
    u16*   ws_attn  = (u16*)(ws + ATTN_OFF);
    u16*   ws_ea    = (u16*)(ws + EA_OFF);
    u16*   ws_v     = (u16*)(ws + V_OFF);
    u16*   ws_reads = ws_v;                    // aliased: v dead after kb
    float* out      = (float*)d_out;

    hipLaunchKernelGGL(kprep, dim3(1), dim3(256), 0, stream,
        key_mem, vp_w, vp_b, summary_w, summary_b, theta_w, theta_b,
        alpha_w, alpha_b, beta_w, beta_b, erase_w, add_w, wf, ewt, awt);
    hipLaunchKernelGGL(ka, dim3(4096), dim3(64), 0, stream,
        questions, responses, qe_w, iv_w, wf, ws_attn, ws_v);
    hipLaunchKernelGGL(kb, dim3(4096), dim3(256), 0, stream,
        ws_v, ewt, erase_b, awt, add_b, ws_ea);
    hipLaunchKernelGGL(k2, dim3(256), dim3(512), 0, stream,
        ws_attn, ws_ea, init_mem, ws_reads);
    hipLaunchKernelGGL(k3, dim3(4096), dim3(64), 0, stream,
        questions, qe_w, ws_reads, wf, out);
}

// Round 4
// 1152.445 us; speedup vs baseline: 1.6950x; 1.6950x over previous
//
#include <hip/hip_runtime.h>
#include <hip/hip_bf16.h>

// ---------------- problem constants ----------------
#define BB   128
#define SS   2048
#define NPOS 262144L   // BB*SS
#define MM   50
#define DK   64
#define DV   128
#define DS   50
#define KN   5

// ---------------- workspace layout (byte offsets) ----------------
// [0, 256KB)   : weight block (fp32 consts + bf16 transposed erase/add)
// [256KB, ..)  : attn bf16 [NPOS][64] (cols 50..63 zero-padded)   33.5 MB
// next         : ea   bf16 [NPOS][256] (erase | add)             134.2 MB
// next         : v    bf16 [NPOS][128]  -- ALIASED later by reads 67.1 MB
// next (opt)   : C    bf16 [NC][B][50][128]  \ adaptive scan-chunk
// next (opt)   : D    bf16 [NC][B][50][128]  / transfer functions
#define EWT_OFF   131072L     // u16 erase_w^T [128][128]
#define AWT_OFF   163840L     // u16 add_w^T   [128][128]
#define ATTN_OFF  262144L
#define EA_OFF    33816576L
#define V_OFF     168034304L
#define WS_BASE   235143168L
#define CD_CHUNK  1638400L    // B*50*128 u16 bytes per chunk per array

// fp32 weight block offsets (floats)
#define KMo  0       // key_mem [50][64]
#define VPWo 3200    // value_proj_w TRANSPOSED [128][69]
#define VPBo 12032   // value_proj_b [128]
#define SWo  12160   // summary_w TRANSPOSED [50][192]
#define SBo  21760   // summary_b [50]
#define TWo  21810   // theta_w [50]
#define AWo  21860   // alpha_w [64]
#define BWo  21924   // beta_w TRANSPOSED [4][64]
#define SCo  22180   // [0]=theta_b [1]=alpha_b [2..5]=beta_b

typedef unsigned short u16;
typedef unsigned int   u32;
typedef __attribute__((ext_vector_type(8))) short   short8;
typedef __attribute__((ext_vector_type(8))) __bf16  bf16x8;
typedef __attribute__((ext_vector_type(4))) float   floatx4;

static __device__ __forceinline__ float b2f(u16 u) {
    union { unsigned int i; float f; } x; x.i = ((unsigned int)u) << 16; return x.f;
}
static __device__ __forceinline__ u16 f2b(float f) {
    union { float f; unsigned int i; } x; x.f = f;
    unsigned int i = x.i;
    return (u16)((i + 0x7fffu + ((i >> 16) & 1u)) >> 16);
}
static __device__ __forceinline__ float fast_tanh(float x) {
    float xc = fminf(15.f, fmaxf(-15.f, x));
    float t = __expf(2.f * xc);
    return (t - 1.f) / (t + 1.f);
}

// ---------------- kprep: pack fp32 weights (+transposes, bf16 for MFMA) ----------------
__global__ __launch_bounds__(256) void kprep(
    const float* km, const float* vpw, const float* vpb,
    const float* sw, const float* sb, const float* tw, const float* tb,
    const float* aw, const float* ab, const float* bw, const float* bb,
    const float* ew_, const float* adw_,
    float* wf, u16* ewt, u16* awt)
{
    int tid = threadIdx.x;
    for (int i = tid; i < 3200; i += 256) wf[KMo + i] = km[i];
    for (int i = tid; i < 8832; i += 256) {           // vpw_t[j][k] = vpw[k][j]
        int j = i / 69, k = i - j * 69;
        wf[VPWo + i] = vpw[k * 128 + j];
    }
    for (int i = tid; i < 128; i += 256) wf[VPBo + i] = vpb[i];
    for (int i = tid; i < 9600; i += 256) {           // sw_t[j][k] = sw[k][j]
        int j = i / 192, k = i - j * 192;
        wf[SWo + i] = sw[k * 50 + j];
    }
    for (int i = tid; i < 50; i += 256) wf[SBo + i] = sb[i];
    for (int i = tid; i < 50; i += 256) wf[TWo + i] = tw[i];
    for (int i = tid; i < 64; i += 256) wf[AWo + i] = aw[i];
    for (int i = tid; i < 256; i += 256) {            // bw_t[j][k] = bw[k][j]
        int j = i >> 6, k = i & 63;
        wf[BWo + i] = bw[k * 4 + j];
    }
    for (int i = tid; i < 16384; i += 256) {          // transpose erase/add -> bf16
        int n = i >> 7, k = i & 127;
        ewt[i] = f2b(ew_[k * 128 + n]);
        awt[i] = f2b(adw_[k * 128 + n]);
    }
    if (tid == 0) wf[SCo + 0] = tb[0];
    if (tid == 1) wf[SCo + 1] = ab[0];
    if (tid >= 2 && tid < 6) wf[SCo + tid] = bb[tid - 2];
}

// ---------------- ka: attn softmax + value projection (lane = position) ----------------
__global__ __launch_bounds__(64) void ka(
    const int* __restrict__ questions, const int* __restrict__ responses,
    const float* __restrict__ qe_w, const float* __restrict__ iv_w,
    const float* __restrict__ wf,
    u16* __restrict__ ws_attn, u16* __restrict__ ws_v)
{
    __shared__ float lgs[64 * 51];
    int lane = threadIdx.x;
    long pos = (long)blockIdx.x * 64 + lane;
    int q = questions[pos];

    float qe[64];
    const float* qrow = qe_w + (long)q * 64;
    #pragma unroll
    for (int c = 0; c < 16; ++c) {
        floatx4 vv = *(const floatx4*)(qrow + c * 4);
        qe[c*4+0] = vv[0]; qe[c*4+1] = vv[1]; qe[c*4+2] = vv[2]; qe[c*4+3] = vv[3];
    }
    const float* kmf = wf + KMo;
    for (int m = 0; m < 50; ++m) {
        float acc = 0.f;
        #pragma unroll
        for (int k = 0; k < 64; ++k) acc = fmaf(qe[k], kmf[m * 64 + k], acc);
        lgs[lane * 51 + m] = acc;
    }
    float mx = -1e30f;
    for (int m = 0; m < 50; ++m) mx = fmaxf(mx, lgs[lane * 51 + m]);
    float sum = 0.f;
    for (int m = 0; m < 50; ++m) {
        float e = __expf(lgs[lane * 51 + m] - mx);
        sum += e; lgs[lane * 51 + m] = e;
    }
    float inv = 1.f / sum;
    u16* adst = ws_attn + pos * 64;
    #pragma unroll
    for (int c = 0; c < 8; ++c) {
        short8 w;
        #pragma unroll
        for (int j = 0; j < 8; ++j) {
            int m = c * 8 + j;
            float val = (m < 50) ? lgs[lane * 51 + m] * inv : 0.f;
            w[j] = (short)f2b(val);
        }
        *(short8*)(adst + c * 8) = w;
    }

    float cat[69];
    const float* irow = iv_w + (long)q * 64;
    #pragma unroll
    for (int c = 0; c < 16; ++c) {
        floatx4 vv = *(const floatx4*)(irow + c * 4);
        cat[c*4+0] = vv[0]; cat[c*4+1] = vv[1]; cat[c*4+2] = vv[2]; cat[c*4+3] = vv[3];
    }
    int r = responses[pos];
    #pragma unroll
    for (int kk = 0; kk < KN; ++kk)
        cat[64 + kk] = fmaxf(1.f - fabsf((float)kk - (float)r) * 0.25f, 0.f);

    const float* vt = wf + VPWo;
    const float* vb = wf + VPBo;
    u16* vdst = ws_v + pos * 128;
    for (int jc = 0; jc < 16; ++jc) {
        short8 wv;
        #pragma unroll
        for (int jj = 0; jj < 8; ++jj) {
            int j = jc * 8 + jj;
            float acc = vb[j];
            #pragma unroll
            for (int k = 0; k < 69; ++k) acc = fmaf(cat[k], vt[j * 69 + k], acc);
            wv[jj] = (short)f2b(acc);
        }
        *(short8*)(vdst + jc * 8) = wv;
    }
}

// ---------------- kb: erase/add GEMM via MFMA + fused activation ----------------
__global__ __launch_bounds__(256) void kb(
    const u16* __restrict__ ws_v,
    const u16* __restrict__ ewt, const float* __restrict__ erase_b,
    const u16* __restrict__ awt, const float* __restrict__ add_b,
    u16* __restrict__ ws_ea)
{
    __shared__ u16 Asm[128 * 128];
    __shared__ u16 Bsm[128 * 128];
    int tid = threadIdx.x;
    int nh = blockIdx.x & 1;
    long rowbase = (long)(blockIdx.x >> 1) * 128;
    const u16*   WT   = nh ? awt : ewt;
    const float* bvec = nh ? add_b : erase_b;

    for (int c = tid; c < 2048; c += 256) {
        int p = c >> 4, k0 = (c & 15) * 8;
        short8 vv = *(const short8*)(ws_v + (rowbase + p) * 128 + k0);
        int cx = (k0 >> 3) ^ (p & 15);
        *(short8*)&Asm[p * 128 + cx * 8] = vv;
    }
    for (int c = tid; c < 2048; c += 256) {
        int n = c >> 4, k0 = (c & 15) * 8;
        short8 vv = *(const short8*)(WT + n * 128 + k0);
        int cx = (k0 >> 3) ^ (n & 15);
        *(short8*)&Bsm[n * 128 + cx * 8] = vv;
    }
    __syncthreads();

    int w = tid >> 6, lane = tid & 63;
    int lrow = lane & 15, quad = lane >> 4;
    floatx4 acc[8][2];
    #pragma unroll
    for (int mi = 0; mi < 8; ++mi)
        #pragma unroll
        for (int nj = 0; nj < 2; ++nj) acc[mi][nj] = (floatx4)0.f;

    #pragma unroll
    for (int kb4 = 0; kb4 < 4; ++kb4) {
        int cx = (kb4 * 4 + quad) ^ lrow;
        bf16x8 afr[8], bfr[2];
        #pragma unroll
        for (int mi = 0; mi < 8; ++mi)
            afr[mi] = *(const bf16x8*)&Asm[(mi * 16 + lrow) * 128 + cx * 8];
        #pragma unroll
        for (int nj = 0; nj < 2; ++nj)
            bfr[nj] = *(const bf16x8*)&Bsm[(w * 32 + nj * 16 + lrow) * 128 + cx * 8];
        #pragma unroll
        for (int mi = 0; mi < 8; ++mi)
            #pragma unroll
            for (int nj = 0; nj < 2; ++nj)
                acc[mi][nj] = __builtin_amdgcn_mfma_f32_16x16x32_bf16(
                    afr[mi], bfr[nj], acc[mi][nj], 0, 0, 0);
    }
    #pragma unroll
    for (int mi = 0; mi < 8; ++mi) {
        #pragma unroll
        for (int nj = 0; nj < 2; ++nj) {
            int ncol = w * 32 + nj * 16 + lrow;
            float bs = bvec[ncol];
            #pragma unroll
            for (int r = 0; r < 4; ++r) {
                int row = mi * 16 + quad * 4 + r;
                float x = acc[mi][nj][r] + bs;
                float y = nh ? fast_tanh(x) : 1.f / (1.f + __expf(-x));
                ws_ea[(rowbase + row) * 256L + nh * 128 + ncol] = f2b(y);
            }
        }
    }
}

// ---------------- kp1: per-chunk affine transfer function (barrier-free) ----------------
// grid = NC*B, block = 128 (one v-column per thread, all 50 m in registers)
__global__ __launch_bounds__(128) void kp1(
    const u16* __restrict__ ws_attn, const u16* __restrict__ ws_ea,
    u16* __restrict__ Cc, u16* __restrict__ Dc, int L)
{
    int b = blockIdx.x & (BB - 1);
    int c = blockIdx.x >> 7;
    int v = threadIdx.x;
    long t0 = (long)b * SS + (long)c * L;

    float C[50], D[50];
    #pragma unroll
    for (int m = 0; m < 50; ++m) { C[m] = 1.f; D[m] = 0.f; }

    float e_r = b2f(ws_ea[t0 * 256 + v]);
    float a_r = b2f(ws_ea[t0 * 256 + 128 + v]);

    for (int t = 0; t < L; ++t) {
        const u32* arow = (const u32*)(ws_attn + (t0 + t) * 64);  // wave-uniform
        u32 ad[25];
        #pragma unroll
        for (int i = 0; i < 25; ++i) ad[i] = arow[i];
        float e = e_r, a = a_r;
        if (t + 1 < L) {
            e_r = b2f(ws_ea[(t0 + t + 1) * 256 + v]);
            a_r = b2f(ws_ea[(t0 + t + 1) * 256 + 128 + v]);
        }
        #pragma unroll
        for (int m = 0; m < 50; ++m) {
            u32 d = ad[m >> 1];
            float w = b2f((u16)((m & 1) ? (d >> 16) : (d & 0xffffu)));
            float cm = fmaf(-w, e, 1.f);
            float wa = w * a;
            D[m] = fmaf(cm, D[m], wa);
            C[m] *= cm;
        }
    }
    long o = ((long)(c * BB + b) * 50) * 128 + v;
    #pragma unroll
    for (int m = 0; m < 50; ++m) {
        Cc[o + (long)m * 128] = f2b(C[m]);
        Dc[o + (long)m * 128] = f2b(D[m]);
    }
}

// ---------------- kcomb: sequential chunk combine -> start states (into C slot) ----------------
__global__ __launch_bounds__(256) void kcomb(
    u16* __restrict__ Cc, const u16* __restrict__ Dc,
    const float* __restrict__ init_mem, int NC)
{
    long i = (long)blockIdx.x * 256 + threadIdx.x;   // over B*50*128
    if (i >= (long)BB * 6400) return;
    int mv = (int)(i % 6400);
    int b  = (int)(i / 6400);
    float s = init_mem[mv];
    long stride = (long)BB * 6400;
    long o = (long)b * 6400 + mv;
    for (int c = 0; c < NC; ++c) {
        float Cv = b2f(Cc[c * stride + o]);
        float Dv = b2f(Dc[c * stride + o]);
        Cc[c * stride + o] = f2b(s);      // overwrite C with chunk-start state
        s = fmaf(Cv, s, Dv);
    }
}

// ---------------- kp2: replay chunk from start state, emit reads (barrier-free) ----------------
__global__ __launch_bounds__(128) void kp2(
    const u16* __restrict__ ws_attn, const u16* __restrict__ ws_ea,
    const u16* __restrict__ Sc, const float* __restrict__ init_mem,
    int L, int useinit, u16* __restrict__ ws_reads)
{
    int b = blockIdx.x & (BB - 1);
    int c = blockIdx.x >> 7;
    int v = threadIdx.x;
    long t0 = (long)b * SS + (long)c * L;

    float mem[50];
    if (useinit) {
        #pragma unroll
        for (int m = 0; m < 50; ++m) mem[m] = init_mem[m * 128 + v];
    } else {
        long o = ((long)(c * BB + b) * 50) * 128 + v;
        #pragma unroll
        for (int m = 0; m < 50; ++m) mem[m] = b2f(Sc[o + (long)m * 128]);
    }
    float e_r = b2f(ws_ea[t0 * 256 + v]);
    float a_r = b2f(ws_ea[t0 * 256 + 128 + v]);

    for (int t = 0; t < L; ++t) {
        const u32* arow = (const u32*)(ws_attn + (t0 + t) * 64);  // wave-uniform
        u32 ad[25];
        #pragma unroll
        for (int i = 0; i < 25; ++i) ad[i] = arow[i];
        float e = e_r, a = a_r;
        if (t + 1 < L) {
            e_r = b2f(ws_ea[(t0 + t + 1) * 256 + v]);
            a_r = b2f(ws_ea[(t0 + t + 1) * 256 + 128 + v]);
        }
        float r0 = 0.f, r1 = 0.f, r2 = 0.f, r3 = 0.f;   // break fma dep chain
        #pragma unroll
        for (int m = 0; m < 50; ++m) {
            u32 d = ad[m >> 1];
            float w = b2f((u16)((m & 1) ? (d >> 16) : (d & 0xffffu)));
            float mv = mem[m];
            switch (m & 3) {
                case 0: r0 = fmaf(w, mv, r0); break;
                case 1: r1 = fmaf(w, mv, r1); break;
                case 2: r2 = fmaf(w, mv, r2); break;
                default: r3 = fmaf(w, mv, r3); break;
            }
            mem[m] = fmaf(w, fmaf(-e, mv, a), mv);
        }
        ws_reads[(t0 + t) * 128 + v] = f2b((r0 + r1) + (r2 + r3));
    }
}

// ---------------- k3: summary/theta/alpha/beta/logits/probs (lane = position) ----------------
__global__ __launch_bounds__(64) void k3(
    const int* __restrict__ questions, const float* __restrict__ qe_w,
    const u16* __restrict__ ws_reads, const float* __restrict__ wf,
    float* __restrict__ out)
{
    __shared__ float accs[64 * 51];
    int lane = threadIdx.x;
    long pos = (long)blockIdx.x * 64 + lane;
    int q = questions[pos];
    const float* swt = wf + SWo;
    const u16* rrow = ws_reads + pos * 128;

    float c[96];
    #pragma unroll
    for (int ch = 0; ch < 12; ++ch) {
        short8 vv = *(const short8*)(rrow + ch * 8);
        #pragma unroll
        for (int i = 0; i < 8; ++i) c[ch * 8 + i] = b2f((u16)vv[i]);
    }
    for (int j = 0; j < 50; ++j) {
        float acc = wf[SBo + j];
        #pragma unroll
        for (int k = 0; k < 96; ++k) acc = fmaf(c[k], swt[j * 192 + k], acc);
        accs[lane * 51 + j] = acc;
    }
    #pragma unroll
    for (int ch = 0; ch < 4; ++ch) {
        short8 vv = *(const short8*)(rrow + 96 + ch * 8);
        #pragma unroll
        for (int i = 0; i < 8; ++i) c[ch * 8 + i] = b2f((u16)vv[i]);
    }
    const float* qrow = qe_w + (long)q * 64;
    #pragma unroll
    for (int ch = 0; ch < 16; ++ch) {
        floatx4 vv = *(const floatx4*)(qrow + ch * 4);
        c[32 + ch*4+0] = vv[0]; c[32 + ch*4+1] = vv[1];
        c[32 + ch*4+2] = vv[2]; c[32 + ch*4+3] = vv[3];
    }
    float dot = 0.f;
    for (int j = 0; j < 50; ++j) {
        float acc = accs[lane * 51 + j];
        #pragma unroll
        for (int k = 0; k < 96; ++k) acc = fmaf(c[k], swt[j * 192 + 96 + k], acc);
        dot = fmaf(fast_tanh(acc), wf[TWo + j], dot);
    }
    float theta = fast_tanh(dot + wf[SCo + 0]);

    float bet[4];
    #pragma unroll
    for (int j = 0; j < 4; ++j) {
        float acc = wf[SCo + 2 + j];
        #pragma unroll
        for (int k = 0; k < 64; ++k) acc = fmaf(c[32 + k], wf[BWo + j * 64 + k], acc);
        bet[j] = acc;
    }
    float al = wf[SCo + 1];
    #pragma unroll
    for (int k = 0; k < 64; ++k) al = fmaf(c[32 + k], wf[AWo + k], al);
    float alpha = (al > 20.f) ? al : log1pf(__expf(al));

    float inter = theta * alpha;
    float l1 = inter - bet[0];
    float l2 = l1 + inter - bet[1];
    float l3 = l2 + inter - bet[2];
    float l4 = l3 + inter - bet[3];
    float mx = fmaxf(0.f, fmaxf(fmaxf(l1, l2), fmaxf(l3, l4)));
    float e0 = __expf(0.f - mx), e1 = __expf(l1 - mx), e2 = __expf(l2 - mx);
    float e3 = __expf(l3 - mx), e4 = __expf(l4 - mx);
    float inv = 1.f / (e0 + e1 + e2 + e3 + e4);

    out[pos] = theta;
    out[NPOS + pos] = alpha;
    float* ob = out + 2L * NPOS + pos * 4;
    ob[0] = bet[0]; ob[1] = bet[1]; ob[2] = bet[2]; ob[3] = bet[3];
    float* ol = out + 6L * NPOS + pos * 5;
    ol[0] = 0.f; ol[1] = l1; ol[2] = l2; ol[3] = l3; ol[4] = l4;
    float* op = out + 11L * NPOS + pos * 5;
    op[0] = e0 * inv; op[1] = e1 * inv; op[2] = e2 * inv;
    op[3] = e3 * inv; op[4] = e4 * inv;
}

// ---------------- host launcher ----------------
extern "C" void kernel_launch(void* const* d_in, const int* in_sizes, int n_in,
                              void* d_out, int out_size, void* d_ws, size_t ws_size,
                              hipStream_t stream)
{
    if (ws_size < (size_t)WS_BASE) return;   // clean fail beats OOB fault

    const int*   questions = (const int*)d_in[0];
    const int*   responses = (const int*)d_in[1];
    const float* qe_w      = (const float*)d_in[2];
    const float* iv_w      = (const float*)d_in[3];
    const float* vp_w      = (const float*)d_in[4];
    const float* vp_b      = (const float*)d_in[5];
    const float* key_mem   = (const float*)d_in[6];
    const float* init_mem  = (const float*)d_in[7];
    const float* erase_w   = (const float*)d_in[8];
    const float* erase_b   = (const float*)d_in[9];
    const float* add_w     = (const float*)d_in[10];
    const float* add_b     = (const float*)d_in[11];
    const float* summary_w = (const float*)d_in[12];
    const float* summary_b = (const float*)d_in[13];
    const float* theta_w   = (const float*)d_in[14];
    const float* theta_b   = (const float*)d_in[15];
    const float* alpha_w   = (const float*)d_in[16];
    const float* alpha_b   = (const float*)d_in[17];
    const float* beta_w    = (const float*)d_in[18];
    const float* beta_b    = (const float*)d_in[19];

    char* ws = (char*)d_ws;
    float* wf       = (float*)ws;
    u16*   ewt      = (u16*)(ws + EWT_OFF);
    u16*   awt      = (u16*)(ws + AWT_OFF);
    u16*   ws_attn  = (u16*)(ws + ATTN_OFF);
    u16*   ws_ea    = (u16*)(ws + EA_OFF);
    u16*   ws_v     = (u16*)(ws + V_OFF);
    u16*   ws_reads = ws_v;                    // aliased: v dead after kb
    float* out      = (float*)d_out;

    // adaptive chunk count for the scan decomposition
    int NC = 16;
    while (NC > 1 && (size_t)WS_BASE + 2UL * (size_t)NC * CD_CHUNK > ws_size) NC >>= 1;
    int L = SS / NC;
    u16* Cc = (u16*)(ws + WS_BASE);
    u16* Dc = (u16*)(ws + WS_BASE + (long)NC * CD_CHUNK);

    hipLaunchKernelGGL(kprep, dim3(1), dim3(256), 0, stream,
        key_mem, vp_w, vp_b, summary_w, summary_b, theta_w, theta_b,
        alpha_w, alpha_b, beta_w, beta_b, erase_w, add_w, wf, ewt, awt);
    hipLaunchKernelGGL(ka, dim3(4096), dim3(64), 0, stream,
        questions, responses, qe_w, iv_w, wf, ws_attn, ws_v);
    hipLaunchKernelGGL(kb, dim3(4096), dim3(256), 0, stream,
        ws_v, ewt, erase_b, awt, add_b, ws_ea);
    if (NC > 1) {
        hipLaunchKernelGGL(kp1, dim3(NC * BB), dim3(128), 0, stream,
            ws_attn, ws_ea, Cc, Dc, L);
        hipLaunchKernelGGL(kcomb, dim3(3200), dim3(256), 0, stream,
            Cc, Dc, init_mem, NC);
        hipLaunchKernelGGL(kp2, dim3(NC * BB), dim3(128), 0, stream,
            ws_attn, ws_ea, Cc, init_mem, L, 0, ws_reads);
    } else {
        hipLaunchKernelGGL(kp2, dim3(BB), dim3(128), 0, stream,
            ws_attn, ws_ea, (const u16*)nullptr, init_mem, SS, 1, ws_reads);
    }
    hipLaunchKernelGGL(k3, dim3(4096), dim3(64), 0, stream,
        questions, qe_w, ws_reads, wf, out);
}

// Round 5
// 696.280 us; speedup vs baseline: 2.8055x; 1.6551x over previous
//
#include <hip/hip_runtime.h>
#include <hip/hip_bf16.h>

// ---------------- problem constants ----------------
#define BB   128
#define SS   2048
#define NPOS 262144L   // BB*SS
#define MM   50
#define DK   64
#define DV   128
#define DS   50
#define KN   5
#define NQ   1000      // distinct questions
#define NC   16        // scan chunks
#define LC   128       // SS/NC

// ---------------- workspace layout (byte offsets) ----------------
#define ATTNQ_OFF  262144L      // fp32 [1000][64] attn rows (softmaxed), cols 50..63 = 0
#define PREQ_OFF   524288L      // fp32 [1000][52] q_e-part of summary (incl. bias)
#define ALQ_OFF    786432L      // fp32 [1000] softplus alpha
#define BQ_OFF     790528L      // fp32 [1000][4] beta
#define EAQ_OFF    1048576L     // fp32 [5000][256] (erase|add rows)
#define READS_OFF  8388608L     // bf16 [NPOS][128]
#define CC_OFF     79691776L    // fp32 [NC][B][50][128]
#define DC_OFF     134217728L   // fp32 [NC][B][50][128]
#define WS_NEEDED  186646528L

// fp32 weight block offsets (floats)
#define KMo   0       // key_mem [50][64]
#define VPWo  3200    // value_proj_w TRANSPOSED [128][69]
#define VPBo  12032   // value_proj_b [128]
#define SWo   12160   // summary_w TRANSPOSED [50][192]
#define SBo   21760   // summary_b [50]
#define TWo   21810   // theta_w [50]
#define AWo   21860   // alpha_w [64]
#define BWo   21924   // beta_w TRANSPOSED [4][64]
#define SCo   22180   // [0]=theta_b [1]=alpha_b [2..5]=beta_b
#define EWTo  22192   // erase_w^T fp32 [128][128]
#define AWTo  38576   // add_w^T   fp32 [128][128]

typedef unsigned short u16;
typedef __attribute__((ext_vector_type(8))) short   short8;
typedef __attribute__((ext_vector_type(4))) float   floatx4;

static __device__ __forceinline__ float b2f(u16 u) {
    union { unsigned int i; float f; } x; x.i = ((unsigned int)u) << 16; return x.f;
}
static __device__ __forceinline__ u16 f2b(float f) {
    union { float f; unsigned int i; } x; x.f = f;
    unsigned int i = x.i;
    return (u16)((i + 0x7fffu + ((i >> 16) & 1u)) >> 16);
}
static __device__ __forceinline__ float fast_tanh(float x) {
    float xc = fminf(15.f, fmaxf(-15.f, x));
    float t = __expf(2.f * xc);
    return (t - 1.f) / (t + 1.f);
}

// ---------------- kprep: pack fp32 weights (+transposes) ----------------
__global__ __launch_bounds__(256) void kprep(
    const float* km, const float* vpw, const float* vpb,
    const float* sw, const float* sb, const float* tw, const float* tb,
    const float* aw, const float* ab, const float* bw, const float* bb,
    const float* ew_, const float* adw_, float* wf)
{
    int tid = threadIdx.x;
    for (int i = tid; i < 3200; i += 256) wf[KMo + i] = km[i];
    for (int i = tid; i < 8832; i += 256) {           // vpw_t[j][k] = vpw[k][j]
        int j = i / 69, k = i - j * 69;
        wf[VPWo + i] = vpw[k * 128 + j];
    }
    for (int i = tid; i < 128; i += 256) wf[VPBo + i] = vpb[i];
    for (int i = tid; i < 9600; i += 256) {           // sw_t[j][k] = sw[k][j]
        int j = i / 192, k = i - j * 192;
        wf[SWo + i] = sw[k * 50 + j];
    }
    for (int i = tid; i < 50; i += 256) wf[SBo + i] = sb[i];
    for (int i = tid; i < 50; i += 256) wf[TWo + i] = tw[i];
    for (int i = tid; i < 64; i += 256) wf[AWo + i] = aw[i];
    for (int i = tid; i < 256; i += 256) {            // bw_t[j][k] = bw[k][j]
        int j = i >> 6, k = i & 63;
        wf[BWo + i] = bw[k * 4 + j];
    }
    for (int i = tid; i < 16384; i += 256) {          // fp32 transposes for kear
        int j = i >> 7, k = i & 127;
        wf[EWTo + i] = ew_[k * 128 + j];
        wf[AWTo + i] = adw_[k * 128 + j];
    }
    if (tid == 0) wf[SCo + 0] = tb[0];
    if (tid == 1) wf[SCo + 1] = ab[0];
    if (tid >= 2 && tid < 6) wf[SCo + tid] = bb[tid - 2];
}

// ---------------- kq: per-question tables (lane = q) ----------------
// attn softmax row, alpha, beta, q_e-part of summary (preq)
__global__ __launch_bounds__(64) void kq(
    const float* __restrict__ qe_w, const float* __restrict__ wf,
    float* __restrict__ attnq, float* __restrict__ preq,
    float* __restrict__ alq, float* __restrict__ bq)
{
    int q = blockIdx.x * 64 + threadIdx.x;
    if (q >= NQ) return;

    float qe[64];
    const float* qrow = qe_w + (long)q * 64;
    #pragma unroll
    for (int c = 0; c < 16; ++c) {
        floatx4 vv = *(const floatx4*)(qrow + c * 4);
        qe[c*4+0] = vv[0]; qe[c*4+1] = vv[1]; qe[c*4+2] = vv[2]; qe[c*4+3] = vv[3];
    }
    // attn logits + softmax in registers
    float lg[50];
    const float* kmf = wf + KMo;
    #pragma unroll 2
    for (int m = 0; m < 50; ++m) {
        float acc = 0.f;
        #pragma unroll
        for (int k = 0; k < 64; ++k) acc = fmaf(qe[k], kmf[m * 64 + k], acc);
        lg[m] = acc;
    }
    float mx = -1e30f;
    #pragma unroll
    for (int m = 0; m < 50; ++m) mx = fmaxf(mx, lg[m]);
    float sum = 0.f;
    #pragma unroll
    for (int m = 0; m < 50; ++m) { lg[m] = __expf(lg[m] - mx); sum += lg[m]; }
    float inv = 1.f / sum;
    float* adst = attnq + q * 64;
    #pragma unroll
    for (int m = 0; m < 50; ++m) adst[m] = lg[m] * inv;
    #pragma unroll
    for (int m = 50; m < 64; ++m) adst[m] = 0.f;

    // preq[j] = summary_b[j] + sum_k qe[k] * sw[128+k][j]
    const float* swt = wf + SWo;
    float* pdst = preq + q * 52;
    #pragma unroll 2
    for (int j = 0; j < 50; ++j) {
        float acc = wf[SBo + j];
        #pragma unroll
        for (int k = 0; k < 64; ++k) acc = fmaf(qe[k], swt[j * 192 + 128 + k], acc);
        pdst[j] = acc;
    }
    pdst[50] = 0.f; pdst[51] = 0.f;

    // alpha (softplus) and beta
    float al = wf[SCo + 1];
    #pragma unroll
    for (int k = 0; k < 64; ++k) al = fmaf(qe[k], wf[AWo + k], al);
    alq[q] = (al > 20.f) ? al : log1pf(__expf(al));
    #pragma unroll
    for (int j = 0; j < 4; ++j) {
        float acc = wf[SCo + 2 + j];
        #pragma unroll
        for (int k = 0; k < 64; ++k) acc = fmaf(qe[k], wf[BWo + j * 64 + k], acc);
        bq[q * 4 + j] = acc;
    }
}

// ---------------- kear: per-(q,r) erase/add rows ----------------
// grid = 5000 blocks, block = 128 (thread = output dim j)
__global__ __launch_bounds__(128) void kear(
    const float* __restrict__ iv_w, const float* __restrict__ wf,
    float* __restrict__ eaq)
{
    __shared__ float vL[128];
    int qr = blockIdx.x;
    int q = qr / 5, r = qr - q * 5;
    int j = threadIdx.x;

    // value embed dim j (item row + weights; item row is wave-uniform -> scalar)
    const float* irow = iv_w + (long)q * 64;
    const float* vt = wf + VPWo + j * 69;
    float acc = wf[VPBo + j];
    #pragma unroll
    for (int k = 0; k < 64; ++k) acc = fmaf(irow[k], vt[k], acc);
    #pragma unroll
    for (int kk = 0; kk < KN; ++kk) {
        float rf = fmaxf(1.f - fabsf((float)kk - (float)r) * 0.25f, 0.f);
        acc = fmaf(rf, vt[64 + kk], acc);
    }
    vL[j] = acc;
    __syncthreads();

    const float* ewt = wf + EWTo + j * 128;
    const float* awt = wf + AWTo + j * 128;
    float ea = 0.f, aa = 0.f;
    #pragma unroll
    for (int k = 0; k < 128; ++k) {
        float v = vL[k];
        ea = fmaf(v, ewt[k], ea);
        aa = fmaf(v, awt[k], aa);
    }
    float* dst = eaq + (long)qr * 256;
    dst[j]       = 1.f / (1.f + __expf(-ea));
    dst[128 + j] = fast_tanh(aa);
}

// ---------------- kp1: per-chunk affine transfer function (barrier-free) ----------------
// grid = NC*B, block = 128 (v-column per thread); attn via wave-uniform scalar loads
__global__ __launch_bounds__(128) void kp1(
    const int* __restrict__ questions, const int* __restrict__ responses,
    const float* __restrict__ attnq, const float* __restrict__ eaq,
    float* __restrict__ Cc, float* __restrict__ Dc)
{
    int b = blockIdx.x & (BB - 1);
    int c = blockIdx.x >> 7;
    int v = threadIdx.x;
    long tb = (long)b * SS + (long)c * LC;

    float C[50], D[50];
    #pragma unroll
    for (int m = 0; m < 50; ++m) { C[m] = 1.f; D[m] = 0.f; }

    int qt = questions[tb];
    int rt = responses[tb];
    const float* ea0 = eaq + (long)(qt * 5 + rt) * 256;
    float e_r = ea0[v], a_r = ea0[128 + v];
    int q_cur = qt;

    for (int t = 0; t < LC; ++t) {
        const float* ar = attnq + q_cur * 64;   // wave-uniform -> s_load
        float e = e_r, a = a_r;
        if (t + 1 < LC) {
            int qn = questions[tb + t + 1];
            int rn = responses[tb + t + 1];
            const float* ean = eaq + (long)(qn * 5 + rn) * 256;
            e_r = ean[v]; a_r = ean[128 + v];
            q_cur = qn;
        }
        #pragma unroll
        for (int m = 0; m < 50; ++m) {
            float w  = ar[m];                   // SGPR
            float cm = fmaf(-w, e, 1.f);
            D[m] = fmaf(cm, D[m], w * a);
            C[m] *= cm;
        }
    }
    long o = ((long)(c * BB + b) * 50) * 128 + v;
    #pragma unroll
    for (int m = 0; m < 50; ++m) {
        Cc[o + (long)m * 128] = C[m];
        Dc[o + (long)m * 128] = D[m];
    }
}

// ---------------- kcomb: sequential chunk combine -> start states (into Cc) ----------------
__global__ __launch_bounds__(256) void kcomb(
    float* __restrict__ Cc, const float* __restrict__ Dc,
    const float* __restrict__ init_mem)
{
    long i = (long)blockIdx.x * 256 + threadIdx.x;   // over B*50*128
    if (i >= (long)BB * 6400) return;
    int mv = (int)(i % 6400);
    int b  = (int)(i / 6400);
    float s = init_mem[mv];
    long stride = (long)BB * 6400;
    long o = (long)b * 6400 + mv;
    for (int c = 0; c < NC; ++c) {
        float Cv = Cc[c * stride + o];
        float Dv = Dc[c * stride + o];
        Cc[c * stride + o] = s;          // overwrite C with chunk-start state
        s = fmaf(Cv, s, Dv);
    }
}

// ---------------- kp2: replay chunk from start state, emit reads ----------------
__global__ __launch_bounds__(128) void kp2(
    const int* __restrict__ questions, const int* __restrict__ responses,
    const float* __restrict__ attnq, const float* __restrict__ eaq,
    const float* __restrict__ Sc, u16* __restrict__ ws_reads)
{
    int b = blockIdx.x & (BB - 1);
    int c = blockIdx.x >> 7;
    int v = threadIdx.x;
    long tb = (long)b * SS + (long)c * LC;

    float mem[50];
    {
        long o = ((long)(c * BB + b) * 50) * 128 + v;
        #pragma unroll
        for (int m = 0; m < 50; ++m) mem[m] = Sc[o + (long)m * 128];
    }
    int qt = questions[tb];
    int rt = responses[tb];
    const float* ea0 = eaq + (long)(qt * 5 + rt) * 256;
    float e_r = ea0[v], a_r = ea0[128 + v];
    int q_cur = qt;

    for (int t = 0; t < LC; ++t) {
        const float* ar = attnq + q_cur * 64;   // wave-uniform -> s_load
        float e = e_r, a = a_r;
        if (t + 1 < LC) {
            int qn = questions[tb + t + 1];
            int rn = responses[tb + t + 1];
            const float* ean = eaq + (long)(qn * 5 + rn) * 256;
            e_r = ean[v]; a_r = ean[128 + v];
            q_cur = qn;
        }
        float racc[4] = {0.f, 0.f, 0.f, 0.f};   // break fma dep chain
        #pragma unroll
        for (int m = 0; m < 50; ++m) {
            float w  = ar[m];                   // SGPR
            float mv = mem[m];
            racc[m & 3] = fmaf(w, mv, racc[m & 3]);
            mem[m] = fmaf(w, fmaf(-e, mv, a), mv);
        }
        ws_reads[(tb + t) * 128 + v] = f2b((racc[0] + racc[1]) + (racc[2] + racc[3]));
    }
}

// ---------------- k3: summary/theta + epilogue via per-q tables (lane = position) ----------------
__global__ __launch_bounds__(64) void k3(
    const int* __restrict__ questions, const u16* __restrict__ ws_reads,
    const float* __restrict__ wf, const float* __restrict__ preq,
    const float* __restrict__ alq, const float* __restrict__ bq,
    float* __restrict__ out)
{
    int lane = threadIdx.x;
    long pos = (long)blockIdx.x * 64 + lane;
    int q = questions[pos];
    const float* swt = wf + SWo;
    const u16* rrow = ws_reads + pos * 128;

    // acc init from preq (floatx4 gathers)
    float acc[52];
    const float* pq = preq + q * 52;
    #pragma unroll
    for (int i = 0; i < 13; ++i) {
        floatx4 p = *(const floatx4*)(pq + i * 4);
        acc[i*4+0] = p[0]; acc[i*4+1] = p[1]; acc[i*4+2] = p[2]; acc[i*4+3] = p[3];
    }
    // half 0: reads[0..63]
    float ch[64];
    #pragma unroll
    for (int cc = 0; cc < 8; ++cc) {
        short8 vv = *(const short8*)(rrow + cc * 8);
        #pragma unroll
        for (int i = 0; i < 8; ++i) ch[cc * 8 + i] = b2f((u16)vv[i]);
    }
    #pragma unroll 2
    for (int j = 0; j < 50; ++j) {
        float a = acc[j];
        #pragma unroll
        for (int k = 0; k < 64; ++k) a = fmaf(ch[k], swt[j * 192 + k], a);
        acc[j] = a;
    }
    // half 1: reads[64..127]
    #pragma unroll
    for (int cc = 0; cc < 8; ++cc) {
        short8 vv = *(const short8*)(rrow + 64 + cc * 8);
        #pragma unroll
        for (int i = 0; i < 8; ++i) ch[cc * 8 + i] = b2f((u16)vv[i]);
    }
    float dot = 0.f;
    #pragma unroll 2
    for (int j = 0; j < 50; ++j) {
        float a = acc[j];
        #pragma unroll
        for (int k = 0; k < 64; ++k) a = fmaf(ch[k], swt[j * 192 + 64 + k], a);
        dot = fmaf(fast_tanh(a), wf[TWo + j], dot);
    }
    float theta = fast_tanh(dot + wf[SCo + 0]);
    float alpha = alq[q];
    floatx4 bet = *(const floatx4*)(bq + q * 4);

    float inter = theta * alpha;
    float l1 = inter - bet[0];
    float l2 = l1 + inter - bet[1];
    float l3 = l2 + inter - bet[2];
    float l4 = l3 + inter - bet[3];
    float mx = fmaxf(0.f, fmaxf(fmaxf(l1, l2), fmaxf(l3, l4)));
    float e0 = __expf(0.f - mx), e1 = __expf(l1 - mx), e2 = __expf(l2 - mx);
    float e3 = __expf(l3 - mx), e4 = __expf(l4 - mx);
    float inv = 1.f / (e0 + e1 + e2 + e3 + e4);

    out[pos] = theta;
    out[NPOS + pos] = alpha;
    float* ob = out + 2L * NPOS + pos * 4;
    ob[0] = bet[0]; ob[1] = bet[1]; ob[2] = bet[2]; ob[3] = bet[3];
    float* ol = out + 6L * NPOS + pos * 5;
    ol[0] = 0.f; ol[1] = l1; ol[2] = l2; ol[3] = l3; ol[4] = l4;
    float* op = out + 11L * NPOS + pos * 5;
    op[0] = e0 * inv; op[1] = e1 * inv; op[2] = e2 * inv;
    op[3] = e3 * inv; op[4] = e4 * inv;
}

// ---------------- host launcher ----------------
extern "C" void kernel_launch(void* const* d_in, const int* in_sizes, int n_in,
                              void* d_out, int out_size, void* d_ws, size_t ws_size,
                              hipStream_t stream)
{
    if (ws_size < (size_t)WS_NEEDED) return;   // clean fail beats OOB fault

    const int*   questions = (const int*)d_in[0];
    const int*   responses = (const int*)d_in[1];
    const float* qe_w      = (const float*)d_in[2];
    const float* iv_w      = (const float*)d_in[3];
    const float* vp_w      = (const float*)d_in[4];
    const float* vp_b      = (const float*)d_in[5];
    const float* key_mem   = (const float*)d_in[6];
    const float* init_mem  = (const float*)d_in[7];
    const float* erase_w   = (const float*)d_in[8];
    const float* erase_b   = (const float*)d_in[9];
    const float* add_w     = (const float*)d_in[10];
    const float* add_b     = (const float*)d_in[11];
    const float* summary_w = (const float*)d_in[12];
    const float* summary_b = (const float*)d_in[13];
    const float* theta_w   = (const float*)d_in[14];
    const float* theta_b   = (const float*)d_in[15];
    const float* alpha_w   = (const float*)d_in[16];
    const float* alpha_b   = (const float*)d_in[17];
    const float* beta_w    = (const float*)d_in[18];
    const float* beta_b    = (const float*)d_in[19];

    char* ws = (char*)d_ws;
    float* wf    = (float*)ws;
    float* attnq = (float*)(ws + ATTNQ_OFF);
    float* preq  = (float*)(ws + PREQ_OFF);
    float* alq   = (float*)(ws + ALQ_OFF);
    float* bq    = (float*)(ws + BQ_OFF);
    float* eaq   = (float*)(ws + EAQ_OFF);
    u16*   ws_reads = (u16*)(ws + READS_OFF);
    float* Cc    = (float*)(ws + CC_OFF);
    float* Dc    = (float*)(ws + DC_OFF);
    float* out   = (float*)d_out;

    hipLaunchKernelGGL(kprep, dim3(1), dim3(256), 0, stream,
        key_mem, vp_w, vp_b, summary_w, summary_b, theta_w, theta_b,
        alpha_w, alpha_b, beta_w, beta_b, erase_w, add_w, wf);
    hipLaunchKernelGGL(kq, dim3(16), dim3(64), 0, stream,
        qe_w, wf, attnq, preq, alq, bq);
    hipLaunchKernelGGL(kear, dim3(5000), dim3(128), 0, stream,
        iv_w, wf, eaq);
    hipLaunchKernelGGL(kp1, dim3(NC * BB), dim3(128), 0, stream,
        questions, responses, attnq, eaq, Cc, Dc);
    hipLaunchKernelGGL(kcomb, dim3(3200), dim3(256), 0, stream,
        Cc, Dc, init_mem);
    hipLaunchKernelGGL(kp2, dim3(NC * BB), dim3(128), 0, stream,
        questions, responses, attnq, eaq, Cc, ws_reads);
    hipLaunchKernelGGL(k3, dim3(4096), dim3(64), 0, stream,
        questions, ws_reads, wf, preq, alq, bq, out);
}